// Round 7
// baseline (154.359 us; speedup 1.0000x reference)
//
#include <hip/hip_runtime.h>

typedef float f32x4 __attribute__((ext_vector_type(4)));
typedef short bf16x8 __attribute__((ext_vector_type(8)));

__device__ __forceinline__ unsigned short f2bf(float f) {
  unsigned u = __builtin_bit_cast(unsigned, f);
  u = (u + 0x7FFFu + ((u >> 16) & 1u)) >> 16;
  return (unsigned short)u;
}

// async global->LDS, 16B per lane. LDS dest = wave-uniform base + lane*16B.
__device__ __forceinline__ void async16(const unsigned short* g, unsigned short* l) {
  __builtin_amdgcn_global_load_lds(
      (__attribute__((address_space(1))) void*)g,
      (__attribute__((address_space(3))) void*)l, 16, 0, 0);
}

// xt padded layout: [b][row 0..129][col 0..129][ch 0..127] bf16, borders zero.
#define XT_ROW 16640              // 130*128 elems per padded row

// ---------------------------------------------------------------------------
// Kernel 1: x (B,C,H,W) f32 -> xt padded bf16 [b][y+1][col+1][c], + row sums
// ---------------------------------------------------------------------------
__global__ __launch_bounds__(256) void k_transpose(const float* __restrict__ x,
                                                   unsigned short* __restrict__ xt,
                                                   float* __restrict__ rowsum) {
  __shared__ unsigned short tile[128][128];
  __shared__ float psum[128][8];
  const int y = blockIdx.x, b = blockIdx.y;
  const int t = threadIdx.x;
  const int colb = (t & 7) * 16;
  const int cp = t >> 3;
  const int swz = (t & 7) << 3;
  for (int ci = 0; ci < 4; ++ci) {
    const int c = ci * 32 + cp;
    const int c2 = c ^ swz;
    const float* src = x + (((size_t)(b * 128 + c) * 128 + y) * 128 + colb);
    float s = 0.f;
#pragma unroll
    for (int j = 0; j < 16; j += 4) {
      float4 v = *(const float4*)(src + j);
      s += v.x + v.y + v.z + v.w;
      tile[colb + j + 0][c2] = f2bf(v.x);
      tile[colb + j + 1][c2] = f2bf(v.y);
      tile[colb + j + 2][c2] = f2bf(v.z);
      tile[colb + j + 3][c2] = f2bf(v.w);
    }
    psum[c][t & 7] = s;
  }
  __syncthreads();
#pragma unroll
  for (int it = 0; it < 8; ++it) {
    const int slot = t + it * 256;
    const int col = slot >> 4;
    const int cg = (slot & 15) * 8;
    const int c2 = cg ^ (((col >> 4) & 7) << 3);
    uint4 vv = *(const uint4*)&tile[col][c2];
    *(uint4*)(xt + (((size_t)b * 130 + y + 1) * 130 + col + 1) * 128 + cg) = vv;
  }
  if (t < 128) {
    float r = 0.f;
#pragma unroll
    for (int j = 0; j < 8; ++j) r += psum[t][j];
    rowsum[((size_t)b * 128 + t) * 128 + y] = r;
  }
}

// ---------------------------------------------------------------------------
// Kernel 1b: zero the padded borders of xt
// ---------------------------------------------------------------------------
__global__ __launch_bounds__(256) void k_border(unsigned short* __restrict__ xt) {
  const int b = blockIdx.y;
  const int idx = blockIdx.x * 256 + threadIdx.x;
  if (idx >= 8256) return;
  int row, col, ck;
  if (idx < 4160) {
    row = (idx < 2080) ? 0 : 129;
    const int s = idx % 2080;
    col = s >> 4;
    ck = s & 15;
  } else {
    const int s = idx - 4160;
    row = (s >> 5) + 1;
    col = (s & 16) ? 129 : 0;
    ck = s & 15;
  }
  uint4 z = {0, 0, 0, 0};
  *(uint4*)(xt + ((size_t)b * 130 + row) * 130 * 128 + (size_t)col * 128 + ck * 8) = z;
}

// ---------------------------------------------------------------------------
// Kernel 2: rowsums -> pooled -> attention MLP -> softmax -> attn, agg_b
// ---------------------------------------------------------------------------
__global__ __launch_bounds__(128) void k_attn(const float* __restrict__ rowsum,
                                              const float* __restrict__ aw1,
                                              const float* __restrict__ ab1,
                                              const float* __restrict__ aw2,
                                              const float* __restrict__ ab2,
                                              const float* __restrict__ bias,
                                              float* __restrict__ attn,
                                              float* __restrict__ aggb) {
  __shared__ float pooled[128];
  __shared__ float h[32];
  __shared__ float at[4];
  const int b = blockIdx.x, t = threadIdx.x;
  const float* rs = rowsum + (size_t)(b * 128 + t) * 128;
  float s = 0.f;
  for (int yy = 0; yy < 128; ++yy) s += rs[yy];
  pooled[t] = s * (1.f / 16384.f);
  __syncthreads();
  if (t < 32) {
    float hv = ab1[t];
    for (int c = 0; c < 128; ++c) hv += pooled[c] * aw1[t * 128 + c];
    h[t] = fmaxf(hv, 0.f);
  }
  __syncthreads();
  if (t < 4) {
    float sc = ab2[t];
    for (int a = 0; a < 32; ++a) sc += h[a] * aw2[t * 32 + a];
    at[t] = sc * (1.f / 30.f);
  }
  __syncthreads();
  if (t == 0) {
    float m = fmaxf(fmaxf(at[0], at[1]), fmaxf(at[2], at[3]));
    float e0 = __expf(at[0] - m), e1 = __expf(at[1] - m);
    float e2 = __expf(at[2] - m), e3 = __expf(at[3] - m);
    float inv = 1.f / (e0 + e1 + e2 + e3);
    at[0] = e0 * inv; at[1] = e1 * inv; at[2] = e2 * inv; at[3] = e3 * inv;
  }
  __syncthreads();
  if (t < 4) attn[b * 4 + t] = at[t];
  float ab = 0.f;
  for (int k = 0; k < 4; ++k) ab += at[k] * bias[k * 128 + t];
  aggb[b * 128 + t] = ab;
}

// ---------------------------------------------------------------------------
// Kernel 3: aggregate weights over K, bf16, slab layout for BK=32:
//   aggw[(((b*36 + s)*128 + o)*32 + kk)], tap = s>>2, c = (s&3)*32 + kk
// ---------------------------------------------------------------------------
__global__ __launch_bounds__(256) void k_aggw(const float* __restrict__ weight,
                                              const float* __restrict__ attn,
                                              unsigned short* __restrict__ aggw) {
  const int fid = blockIdx.x * 256 + threadIdx.x;
  const int kk = fid & 31;
  const int o = (fid >> 5) & 127;
  const int rest = fid >> 12;      // b*36 + s
  const int s = rest % 36;
  const int b = rest / 36;
  const int c = ((s & 3) << 5) + kk;
  const int pq = s >> 2;
  const size_t src = (size_t)o * 1152 + (size_t)c * 9 + pq;
  float v = attn[b * 4 + 0] * weight[src]
          + attn[b * 4 + 1] * weight[src + 147456]
          + attn[b * 4 + 2] * weight[src + 2 * 147456]
          + attn[b * 4 + 3] * weight[src + 3 * 147456];
  aggw[fid] = f2bf(v);
}

// ---------------------------------------------------------------------------
// Kernel 4: conv implicit GEMM with x-window RESIDENT in LDS.
// Block = (b, y0..y0+1): M=128(Cout) x N=256(2 rows x 128 cols), K=1152 in 36
// steps of BK=32. 512 threads / 8 waves (2M x 4N), wave tile 64x64.
// LDS: xrows[4][130][128] (133KB, staged ONCE, 16-slot XOR swizzle) +
// A tri-buffer 3x[128][32] (24KB, streamed, counted vmcnt(1), 2-ahead).
// Eliminates the 4.3x redundant B staging that made round 6 L2-BW-bound.
// ---------------------------------------------------------------------------
__global__ __launch_bounds__(512, 2) void k_conv(const unsigned short* __restrict__ xt,
                                                 const unsigned short* __restrict__ aggw,
                                                 const float* __restrict__ aggb,
                                                 float* __restrict__ out) {
  __shared__ unsigned short lds[78848];  // xrows @0 (66560 elems), A @66560 (3*4096)
  const int id = blockIdx.x;
  const int swz = (id & 7) * 128 + (id >> 3);   // 1024 % 8 == 0: bijective
  const int b = swz >> 6;
  const int y0 = (swz & 63) * 2;
  const int t = threadIdx.x;
  const int lane = t & 63, w = t >> 6;
  const int mw = w >> 2, nw = w & 3;
  const int l15 = lane & 15, lk = lane >> 4;

  // ---- prologue: stage 4 padded x rows (padded idx y0 .. y0+3), swizzled --
  // chunk idx -> row = idx/2080, col = (idx%2080)>>4, k8 = idx&15
  // LDS[row][col][slot k8] = xt[row][col][slot k8 ^ (col&15)]
  {
    const unsigned short* xb = xt + (size_t)(b * 130 + y0) * XT_ROW;
#pragma unroll
    for (int i = 0; i < 16; ++i) {
      const int idx = i * 512 + t;
      const int row = idx / 2080, rem = idx % 2080;
      const int col = rem >> 4, k8 = rem & 15;
      async16(xb + (row * 130 + col) * 128 + ((k8 ^ (col & 15)) * 8),
              &lds[0] + i * 4096 + w * 512);
    }
    if (w < 2) {
      const int idx = 8192 + t;           // threads 0..127 only (waves 0,1)
      const int row = idx / 2080, rem = idx % 2080;
      const int col = rem >> 4, k8 = rem & 15;
      async16(xb + (row * 130 + col) * 128 + ((k8 ^ (col & 15)) * 8),
              &lds[0] + 65536 + w * 512);
    }
  }
  // ---- A staging: 1 chunk/thread/step; slot XOR (n>>1)&3 (max 2-way) ------
  const int an = t >> 2, ak8 = t & 3;
  const unsigned short* aS = aggw + (size_t)b * 147456 + an * 32
                           + ((ak8 ^ ((an >> 1) & 3)) * 8);
  unsigned short* aldsw = &lds[66560] + w * 512;

#define STAGE_A(buf, s) async16(aS + (s) * 4096, aldsw + (buf) * 4096)

  STAGE_A(0, 0);
  STAGE_A(1, 1);

  const int rbase = (nw >> 1) * 16640;            // y-row select (r*130*128)
  const int px0 = (nw & 1) * 64 + l15;
  f32x4 acc[4][4] = {};

#pragma unroll
  for (int s = 0; s < 36; ++s) {
    const int tap = s >> 2, cc = s & 3;
    const int p = tap / 3, q = tap - 3 * p;
    if (s < 35) { asm volatile("s_waitcnt vmcnt(1)" ::: "memory"); }
    else        { asm volatile("s_waitcnt vmcnt(0)" ::: "memory"); }
    __builtin_amdgcn_sched_barrier(0);
    __builtin_amdgcn_s_barrier();
    __builtin_amdgcn_sched_barrier(0);

    const unsigned short* A0 = &lds[66560 + (s % 3) * 4096];
    bf16x8 af[4], bfr[4];
#pragma unroll
    for (int mi = 0; mi < 4; ++mi) {
      const int row = mw * 64 + mi * 16 + l15;
      af[mi] = *(const bf16x8*)(A0 + row * 32 + ((lk ^ ((row >> 1) & 3)) * 8));
    }
#pragma unroll
    for (int ni = 0; ni < 4; ++ni) {
      const int col = px0 + ni * 16 + q;          // padded input col
      bfr[ni] = *(const bf16x8*)(&lds[0] + rbase + p * 16640 + col * 128
                                 + (((cc * 4 + lk) ^ (col & 15)) * 8));
    }
    if (s + 2 < 36) STAGE_A((s + 2) % 3, s + 2);
    __builtin_amdgcn_sched_barrier(0);
    asm volatile("s_waitcnt lgkmcnt(0)" ::: "memory");
    __builtin_amdgcn_sched_barrier(0);
    __builtin_amdgcn_s_setprio(1);
#pragma unroll
    for (int mi = 0; mi < 4; ++mi)
#pragma unroll
      for (int ni = 0; ni < 4; ++ni)
        acc[mi][ni] = __builtin_amdgcn_mfma_f32_16x16x32_bf16(af[mi], bfr[ni], acc[mi][ni], 0, 0, 0);
    __builtin_amdgcn_s_setprio(0);
    __builtin_amdgcn_sched_barrier(0);
  }
#undef STAGE_A

  // epilogue: wave (mw,nw): y = y0 + (nw>>1), colb = (nw&1)*64 + l15
  const int y = y0 + (nw >> 1);
  const int colb = (nw & 1) * 64 + l15;
#pragma unroll
  for (int mi = 0; mi < 4; ++mi) {
    const int o = mw * 64 + mi * 16 + lk * 4;
#pragma unroll
    for (int rr = 0; rr < 4; ++rr) {
      const float bsv = aggb[b * 128 + o + rr];
      float* orow = out + ((size_t)(b * 128 + o + rr) * 128 + y) * 128 + colb;
      orow[0]  = acc[mi][0][rr] + bsv;
      orow[16] = acc[mi][1][rr] + bsv;
      orow[32] = acc[mi][2][rr] + bsv;
      orow[48] = acc[mi][3][rr] + bsv;
    }
  }
}

// ---------------------------------------------------------------------------
extern "C" void kernel_launch(void* const* d_in, const int* in_sizes, int n_in,
                              void* d_out, int out_size, void* d_ws, size_t ws_size,
                              hipStream_t stream) {
  const float* x      = (const float*)d_in[0];
  const float* weight = (const float*)d_in[1];
  const float* bias   = (const float*)d_in[2];
  const float* aw1    = (const float*)d_in[3];
  const float* ab1    = (const float*)d_in[4];
  const float* aw2    = (const float*)d_in[5];
  const float* ab2    = (const float*)d_in[6];
  float* out = (float*)d_out;

  char* ws = (char*)d_ws;
  unsigned short* xt   = (unsigned short*)ws;                        // 69,222,400 B
  unsigned short* aggw = (unsigned short*)(ws + 69222400);           //  4,718,592 B
  float* rowsum        = (float*)(ws + 69222400 + 4718592);          //  1,048,576 B
  float* attn          = (float*)(ws + 69222400 + 4718592 + 1048576);         // 256 B
  float* aggb          = (float*)(ws + 69222400 + 4718592 + 1048576 + 256);   // 8 KB

  hipLaunchKernelGGL(k_border, dim3(33, 16), dim3(256), 0, stream, xt);
  hipLaunchKernelGGL(k_transpose, dim3(128, 16), dim3(256), 0, stream, x, xt, rowsum);
  hipLaunchKernelGGL(k_attn, dim3(16), dim3(128), 0, stream,
                     rowsum, aw1, ab1, aw2, ab2, bias, attn, aggb);
  hipLaunchKernelGGL(k_aggw, dim3(9216), dim3(256), 0, stream, weight, attn, aggw);
  hipLaunchKernelGGL(k_conv, dim3(1024), dim3(512), 0, stream, xt, aggw, aggb, out);
}